// Round 5
// baseline (23933.269 us; speedup 1.0000x reference)
//
#include <hip/hip_runtime.h>

// ---------------------------------------------------------------------------
// LSTM T=2048, B=256, IN=64, H=256 (gates 4H=1024)
// R5: 2-WG teams (column halves), weights register-resident (160 regs/wave).
// Exchange rebuilt fence-free:
//   producer: wave-private LDS transpose -> publish [row][col] hi/lo (sc1
//             atomic stores) -> s_waitcnt vmcnt(0) -> relaxed atomicAdd ctr.
//   consumer: ctr pre-checked end of prev step; relaxed spin; coalesced 8B
//             agent-atomic loads DIRECTLY into MFMA A-regs. No fences, no L2
//             invalidate, no mid-step barrier. One barrier per step.
// LDS A-region XOR-swizzled (^((row&7)<<4)) -> conflict-free frag reads.
// Numerics identical to R1/R2b: bf16 weights, hi/lo bf16 A, fp32 acc.
// ---------------------------------------------------------------------------

#define T_SEQ 2048
#define B_SZ  256
#define IN_SZ 64
#define H_SZ  256
#define G4    1024
#define NKF   10
#define NCT   64
#define FRAG_BYTES (NCT * NKF * 64 * 16)      // 655360 B
#define BIAS_OFF   FRAG_BYTES
#define FLAGS_OFF  (FRAG_BYTES + 4096)
#define XBUF_OFF   (FRAG_BYTES + 8192)        // 32 wg * 2 slots * 8KB = 512KB
// LDS: 2 buf * 16 rows * 768 B (A matrix) + 8704 B pubstage = 33280 B
#define ROW_B   768
#define BUF_B   (16 * ROW_B)                  // 12288
#define PUB_OFF (2 * BUF_B)                   // 24576

typedef float f32x4 __attribute__((ext_vector_type(4)));
typedef short s16x8 __attribute__((ext_vector_type(8)));
typedef short s16x2 __attribute__((ext_vector_type(2)));
typedef unsigned long long u64;
typedef u64 u64x2 __attribute__((ext_vector_type(2)));

__device__ __forceinline__ short f2bf(float f) {          // RNE f32->bf16
    unsigned u = __builtin_bit_cast(unsigned, f);
    u = u + 0x7fffu + ((u >> 16) & 1u);
    return (short)(u >> 16);
}
__device__ __forceinline__ float bf2f(short s) {
    return __builtin_bit_cast(float, ((unsigned)(unsigned short)s) << 16);
}
__device__ __forceinline__ float fsigmoid(float v) {
    return __builtin_amdgcn_rcpf(1.0f + __expf(-v));
}
__device__ __forceinline__ float ftanh(float v) {
    return 2.0f * __builtin_amdgcn_rcpf(1.0f + __expf(-2.0f * v)) - 1.0f;
}
// A-region byte address: row-major 768B rows, XOR-swizzled within row.
// Row layout (bytes): [0,128) x_hi | [128,384) own-h hi | +384 same for lo.
__device__ __forceinline__ short* aptr(char* lds, int buf, int row, int off) {
    return (short*)(lds + buf * BUF_B + row * ROW_B + (off ^ ((row & 7) << 4)));
}

// --- repack Wx|Wh into bf16 MFMA B-fragments (unchanged layout) ------------
// fragment (ct,kf), lane l, elem j <-> k = kf*32 + (l>>4)*8 + j, n = ct*16+(l&15)
__global__ void repack_kernel(const float* __restrict__ Wx,
                              const float* __restrict__ Wh,
                              const float* __restrict__ bx,
                              const float* __restrict__ bh,
                              s16x8* __restrict__ fragbuf,
                              float* __restrict__ bias) {
    const int blk  = blockIdx.x;
    const int lane = threadIdx.x;
    const int ct = blk / NKF;
    const int kf = blk - ct * NKF;
    const int n  = ct * 16 + (lane & 15);
    const int q  = lane >> 4;
    s16x8 frag;
#pragma unroll
    for (int j = 0; j < 8; ++j) {
        const int k = kf * 32 + q * 8 + j;
        const float v = (k < IN_SZ) ? Wx[k * G4 + n] : Wh[(k - IN_SZ) * G4 + n];
        frag[j] = f2bf(v);
    }
    fragbuf[blk * 64 + lane] = frag;
    if (blk < 16) {
        const int i = blk * 64 + lane;
        bias[i] = bx[i] + bh[i];
    }
}

__global__ void init_flags(unsigned* __restrict__ flags) {
    if (threadIdx.x < 32) flags[threadIdx.x] = 0u;
}

__global__ __launch_bounds__(512, 2) void lstm_persist(
        const float* __restrict__ x,
        const s16x8* __restrict__ fragbuf,
        const float* __restrict__ bias,
        float* __restrict__ out,
        unsigned* __restrict__ flags,
        char* __restrict__ xbuf) {
    __shared__ char lds[PUB_OFF + 8704];

    const int tid  = threadIdx.x;
    const int lane = tid & 63;
    const int w    = tid >> 6;
    const int q    = lane >> 4;
    const int ln   = lane & 15;
    const int bid  = blockIdx.x;
    const int g    = bid >> 1;
    const int p    = bid & 1;
    const int peer = bid ^ 1;
    const int S    = g * 16;
    const int hb   = p * 8 + w;
    const int col  = hb * 16 + ln;        // global hidden col
    const int colp = w * 16 + ln;         // col within own half

    for (int i = tid; i < (PUB_OFF + 8704) / 4; i += 512)
        ((int*)lds)[i] = 0;

    // weights: wt[ci][j], j order: 0,1=x; 2..5=own h; 6..9=peer h
    s16x8 wt[4][10];
#pragma unroll
    for (int ci = 0; ci < 4; ++ci) {
        const int ct = ci * 16 + hb;
#pragma unroll
        for (int j = 0; j < 10; ++j) {
            const int kf = (j < 2) ? j
                         : (j < 6 ? 2 + 4 * p + (j - 2)
                                  : 2 + 4 * (1 - p) + (j - 6));
            wt[ci][j] = fragbuf[(size_t)(ct * NKF + kf) * 64 + lane];
        }
    }
    float bs[4];
#pragma unroll
    for (int ci = 0; ci < 4; ++ci) bs[ci] = bias[(ci * 16 + hb) * 16 + ln];

    f32x4 cs = {0.f, 0.f, 0.f, 0.f};

    const int xrow = tid >> 5;
    const int xi   = (tid & 31) << 1;
    const float* xp0 = x + (size_t)(S + xrow) * IN_SZ + xi;
    float xv0 = xp0[0], xv1 = xp0[1];                       // x_0

    // stage x_0 into buf 0
    {
        const short h0 = f2bf(xv0), h1 = f2bf(xv1);
        const short l0 = f2bf(xv0 - bf2f(h0));
        const short l1 = f2bf(xv1 - bf2f(h1));
        *(s16x2*)aptr(lds, 0, xrow, xi * 2)       = (s16x2){h0, h1};
        *(s16x2*)aptr(lds, 0, xrow, 384 + xi * 2) = (s16x2){l0, l1};
    }
    {   // prefetch x_1
        const float* xp = xp0 + (size_t)(B_SZ * IN_SZ);
        xv0 = xp[0]; xv1 = xp[1];
    }
    unsigned* psw = (unsigned*)(lds + PUB_OFF) + w * 272;   // wave-private 16x17
    unsigned rdyflag = 0;

    __syncthreads();

    for (int t = 0; t < T_SEQ; ++t) {
        const int cur = t & 1;
        char* mySlot = xbuf + (size_t)bid  * 16384 + (size_t)cur * 8192;
        char* pSlot  = xbuf + (size_t)peer * 16384 + (size_t)((t - 1) & 1) * 8192;
        const unsigned tgt = 8u * (unsigned)t;
        bool ready = (t > 0) && (rdyflag >= tgt);

        // ---- fast path: peer data already published -> loads fly under MFMA
        u64 ph[8], pl[8];
        if (ready) {
#pragma unroll
            for (int jj = 0; jj < 4; ++jj) {
                const int off = ln * 256 + jj * 64 + q * 16;
                ph[2*jj]   = __hip_atomic_load((const u64*)(pSlot + off),       __ATOMIC_RELAXED, __HIP_MEMORY_SCOPE_AGENT);
                ph[2*jj+1] = __hip_atomic_load((const u64*)(pSlot + off + 8),   __ATOMIC_RELAXED, __HIP_MEMORY_SCOPE_AGENT);
                pl[2*jj]   = __hip_atomic_load((const u64*)(pSlot + 4096 + off),__ATOMIC_RELAXED, __HIP_MEMORY_SCOPE_AGENT);
                pl[2*jj+1] = __hip_atomic_load((const u64*)(pSlot + 4104 + off),__ATOMIC_RELAXED, __HIP_MEMORY_SCOPE_AGENT);
            }
        }

        // ---- x + own-half MFMAs (j = 0..5) ----
        f32x4 acc[4], acl[4];
#pragma unroll
        for (int ci = 0; ci < 4; ++ci) {
            acc[ci] = (f32x4){bs[ci], bs[ci], bs[ci], bs[ci]};
            acl[ci] = (f32x4){0.f, 0.f, 0.f, 0.f};
        }
#pragma unroll
        for (int j = 0; j < 6; ++j) {
            const s16x8 ah = *(const s16x8*)aptr(lds, cur, ln, j * 64 + q * 16);
            const s16x8 al = *(const s16x8*)aptr(lds, cur, ln, 384 + j * 64 + q * 16);
#pragma unroll
            for (int ci = 0; ci < 4; ++ci) {
                acc[ci] = __builtin_amdgcn_mfma_f32_16x16x32_bf16(ah, wt[ci][j], acc[ci], 0, 0, 0);
                acl[ci] = __builtin_amdgcn_mfma_f32_16x16x32_bf16(al, wt[ci][j], acl[ci], 0, 0, 0);
            }
        }

        // ---- peer-half MFMAs (j = 6..9) ----
        if (t > 0) {
            if (!ready) {
                while (__hip_atomic_load(&flags[peer], __ATOMIC_RELAXED,
                                         __HIP_MEMORY_SCOPE_AGENT) < tgt)
                    __builtin_amdgcn_s_sleep(1);
                asm volatile("" ::: "memory");
#pragma unroll
                for (int jj = 0; jj < 4; ++jj) {
                    const int off = ln * 256 + jj * 64 + q * 16;
                    ph[2*jj]   = __hip_atomic_load((const u64*)(pSlot + off),       __ATOMIC_RELAXED, __HIP_MEMORY_SCOPE_AGENT);
                    ph[2*jj+1] = __hip_atomic_load((const u64*)(pSlot + off + 8),   __ATOMIC_RELAXED, __HIP_MEMORY_SCOPE_AGENT);
                    pl[2*jj]   = __hip_atomic_load((const u64*)(pSlot + 4096 + off),__ATOMIC_RELAXED, __HIP_MEMORY_SCOPE_AGENT);
                    pl[2*jj+1] = __hip_atomic_load((const u64*)(pSlot + 4104 + off),__ATOMIC_RELAXED, __HIP_MEMORY_SCOPE_AGENT);
                }
            }
#pragma unroll
            for (int jj = 0; jj < 4; ++jj) {
                const s16x8 ah = __builtin_bit_cast(s16x8, (u64x2){ph[2*jj], ph[2*jj+1]});
                const s16x8 al = __builtin_bit_cast(s16x8, (u64x2){pl[2*jj], pl[2*jj+1]});
#pragma unroll
                for (int ci = 0; ci < 4; ++ci) {
                    acc[ci] = __builtin_amdgcn_mfma_f32_16x16x32_bf16(ah, wt[ci][6 + jj], acc[ci], 0, 0, 0);
                    acl[ci] = __builtin_amdgcn_mfma_f32_16x16x32_bf16(al, wt[ci][6 + jj], acl[ci], 0, 0, 0);
                }
            }
        }
#pragma unroll
        for (int ci = 0; ci < 4; ++ci) acc[ci] += acl[ci];

        // ---- cell update ----
        // C/D layout (m89): col = lane&15, row = (lane>>4)*4 + r
        const bool last = (t == T_SEQ - 1);
        float hvr[4]; float cfr[4]; unsigned pu[4];
#pragma unroll
        for (int r = 0; r < 4; ++r) {
            const float fv = fsigmoid(acc[0][r]);
            const float iv = fsigmoid(acc[1][r]);
            const float ov = fsigmoid(acc[2][r]);
            const float gv = ftanh(acc[3][r]);
            const float cf = fv * cs[r] + iv * gv;
            cs[r] = cf; cfr[r] = cf;
            const float hv = ov * ftanh(cf);
            hvr[r] = hv;
            const short hh = f2bf(hv);
            const short hl = f2bf(hv - bf2f(hh));
            pu[r] = ((unsigned)(unsigned short)hh)
                  | (((unsigned)(unsigned short)hl) << 16);
        }

        // ---- publish: wave-private LDS transpose -> [row][col] hi/lo ----
#pragma unroll
        for (int r = 0; r < 4; ++r) psw[ln * 17 + q * 4 + r] = pu[r];
        {
            const int m2 = lane & 15;          // row role
            const int cc = lane >> 4;          // col-chunk role
            const unsigned t0 = psw[(cc * 4 + 0) * 17 + m2];
            const unsigned t1 = psw[(cc * 4 + 1) * 17 + m2];
            const unsigned t2 = psw[(cc * 4 + 2) * 17 + m2];
            const unsigned t3 = psw[(cc * 4 + 3) * 17 + m2];
            const u64 hi64 = (u64)(t0 & 0xffffu) | ((u64)(t1 & 0xffffu) << 16)
                           | ((u64)(t2 & 0xffffu) << 32) | ((u64)(t3 & 0xffffu) << 48);
            const u64 lo64 = (u64)(t0 >> 16) | ((u64)(t1 >> 16) << 16)
                           | ((u64)(t2 >> 16) << 32) | ((u64)(t3 >> 16) << 48);
            const int off = m2 * 256 + w * 32 + cc * 8;
            __hip_atomic_store((u64*)(mySlot + off),        hi64, __ATOMIC_RELAXED, __HIP_MEMORY_SCOPE_AGENT);
            __hip_atomic_store((u64*)(mySlot + 4096 + off), lo64, __ATOMIC_RELAXED, __HIP_MEMORY_SCOPE_AGENT);
        }
        // drain publish stores to LLC, then signal (one inc per wave)
        asm volatile("s_waitcnt vmcnt(0)" ::: "memory");
        if (lane == 0)
            (void)__hip_atomic_fetch_add(&flags[bid], 1u, __ATOMIC_RELAXED,
                                         __HIP_MEMORY_SCOPE_AGENT);

        // ---- off-critical-path tail: h_seq, next-step staging ----
        float* hs = out + (size_t)t * (B_SZ * H_SZ) + (size_t)S * H_SZ;
#pragma unroll
        for (int r = 0; r < 4; ++r) {
            const int m = q * 4 + r;
            __builtin_nontemporal_store(hvr[r], hs + m * H_SZ + col);
            *aptr(lds, cur ^ 1, m, 128 + colp * 2) = (short)(pu[r] & 0xffffu);
            *aptr(lds, cur ^ 1, m, 512 + colp * 2) = (short)(pu[r] >> 16);
            if (last) {
                float* fin = out + (size_t)T_SEQ * B_SZ * H_SZ;
                fin[(S + m) * H_SZ + col] = hvr[r];
                fin[B_SZ * H_SZ + (S + m) * H_SZ + col] = cfr[r];
            }
        }
        {   // stage x_{t+1} (prefetched), prefetch x_{t+2}
            const short h0 = f2bf(xv0), h1 = f2bf(xv1);
            const short l0 = f2bf(xv0 - bf2f(h0));
            const short l1 = f2bf(xv1 - bf2f(h1));
            *(s16x2*)aptr(lds, cur ^ 1, xrow, xi * 2)       = (s16x2){h0, h1};
            *(s16x2*)aptr(lds, cur ^ 1, xrow, 384 + xi * 2) = (s16x2){l0, l1};
            const int tn = (t + 2 < T_SEQ) ? t + 2 : T_SEQ - 1;
            const float* xp = xp0 + (size_t)tn * (B_SZ * IN_SZ);
            xv0 = xp[0]; xv1 = xp[1];
        }
        // pre-check peer flag for next step (hides its latency)
        rdyflag = __hip_atomic_load(&flags[peer], __ATOMIC_RELAXED,
                                    __HIP_MEMORY_SCOPE_AGENT);
        __syncthreads();
    }
}

extern "C" void kernel_launch(void* const* d_in, const int* in_sizes, int n_in,
                              void* d_out, int out_size, void* d_ws, size_t ws_size,
                              hipStream_t stream) {
    const float* x  = (const float*)d_in[0];
    const float* Wx = (const float*)d_in[1];
    const float* Wh = (const float*)d_in[2];
    const float* bx = (const float*)d_in[3];
    const float* bh = (const float*)d_in[4];
    float* out = (float*)d_out;

    s16x8*    fragbuf = (s16x8*)d_ws;
    float*    bias    = (float*)((char*)d_ws + BIAS_OFF);
    unsigned* flags   = (unsigned*)((char*)d_ws + FLAGS_OFF);
    char*     xbuf    = (char*)d_ws + XBUF_OFF;

    repack_kernel<<<NCT * NKF, 64, 0, stream>>>(Wx, Wh, bx, bh, fragbuf, bias);
    init_flags<<<1, 64, 0, stream>>>(flags);
    lstm_persist<<<32, 512, 0, stream>>>(x, fragbuf, bias, out, flags, xbuf);
}

// Round 7
// 12012.611 us; speedup vs baseline: 1.9923x; 1.9923x over previous
//
#include <hip/hip_runtime.h>

// ---------------------------------------------------------------------------
// LSTM T=2048, B=256, IN=64, H=256 (gates 4H=1024)
// R6: 2-WG teams (column halves), weights register-resident (160 regs/wave).
// Exchange: producer transposes via wave-private LDS, publishes [row][col]
// hi/lo as sc1 stores, vmcnt(0), per-wave relaxed atomicAdd on a PADDED flag.
// Consumer: flag pre-checked at END of previous step (required for spec
// correctness); fast path issues ONE coalesced 16B sc1 load/thread at step
// start (RT hidden under own-half MFMAs), stages to a peer LDS region,
// mid-step barrier, peer MFMAs from LDS. Slow path spins after own MFMAs.
// 1x slice traffic (8KB/WG/step) -- fixes R5's 8x sc1 amplification.
// No fences anywhere. Numerics identical to R4/R5.
// ---------------------------------------------------------------------------

#define T_SEQ 2048
#define B_SZ  256
#define IN_SZ 64
#define H_SZ  256
#define G4    1024
#define NKF   10
#define NCT   64
#define FRAG_BYTES (NCT * NKF * 64 * 16)      // 655360 B
#define BIAS_OFF   FRAG_BYTES
#define FLAGS_OFF  (FRAG_BYTES + 8192)        // 32 flags, 128B apart (4KB)
#define XBUF_OFF   (FRAG_BYTES + 16384)       // 32 wg * 2 slots * 8KB = 512KB
// LDS map
#define ROW_B    768
#define BUF_B    (16 * ROW_B)                 // 12288
#define PEER_OFF (2 * BUF_B)                  // 24576; 16 rows * 544B = 8704
#define PROW     544
#define PSW_OFF  (PEER_OFF + 8704)            // 33280; 8 waves * 1088B = 8704
#define LDS_BYTES (PSW_OFF + 8704)            // 41984

typedef float f32x4 __attribute__((ext_vector_type(4)));
typedef short s16x8 __attribute__((ext_vector_type(8)));
typedef short s16x2 __attribute__((ext_vector_type(2)));
typedef unsigned long long u64;
typedef u64 u64x2 __attribute__((ext_vector_type(2)));

__device__ __forceinline__ short f2bf(float f) {          // RNE f32->bf16
    unsigned u = __builtin_bit_cast(unsigned, f);
    u = u + 0x7fffu + ((u >> 16) & 1u);
    return (short)(u >> 16);
}
__device__ __forceinline__ float bf2f(short s) {
    return __builtin_bit_cast(float, ((unsigned)(unsigned short)s) << 16);
}
__device__ __forceinline__ float fsigmoid(float v) {
    return __builtin_amdgcn_rcpf(1.0f + __expf(-v));
}
__device__ __forceinline__ float ftanh(float v) {
    return 2.0f * __builtin_amdgcn_rcpf(1.0f + __expf(-2.0f * v)) - 1.0f;
}
// Own A-matrix rows (x + own-h), 768B rows, XOR-swizzled within row.
__device__ __forceinline__ short* aptr(char* lds, int buf, int row, int off) {
    return (short*)(lds + buf * BUF_B + row * ROW_B + (off ^ ((row & 7) << 4)));
}

// --- repack Wx|Wh into bf16 MFMA B-fragments -------------------------------
// fragment (ct,kf), lane l, elem j <-> k = kf*32 + (l>>4)*8 + j, n = ct*16+(l&15)
__global__ void repack_kernel(const float* __restrict__ Wx,
                              const float* __restrict__ Wh,
                              const float* __restrict__ bx,
                              const float* __restrict__ bh,
                              s16x8* __restrict__ fragbuf,
                              float* __restrict__ bias) {
    const int blk  = blockIdx.x;
    const int lane = threadIdx.x;
    const int ct = blk / NKF;
    const int kf = blk - ct * NKF;
    const int n  = ct * 16 + (lane & 15);
    const int q  = lane >> 4;
    s16x8 frag;
#pragma unroll
    for (int j = 0; j < 8; ++j) {
        const int k = kf * 32 + q * 8 + j;
        const float v = (k < IN_SZ) ? Wx[k * G4 + n] : Wh[(k - IN_SZ) * G4 + n];
        frag[j] = f2bf(v);
    }
    fragbuf[blk * 64 + lane] = frag;
    if (blk < 16) {
        const int i = blk * 64 + lane;
        bias[i] = bx[i] + bh[i];
    }
}

__global__ void init_flags(unsigned* __restrict__ flags) {
    for (int i = threadIdx.x; i < 1024; i += 256) flags[i] = 0u;
}

__global__ __launch_bounds__(512, 2) void lstm_persist(
        const float* __restrict__ x,
        const s16x8* __restrict__ fragbuf,
        const float* __restrict__ bias,
        float* __restrict__ out,
        unsigned* __restrict__ flags,
        char* __restrict__ xbuf) {
    __shared__ char lds[LDS_BYTES];

    const int tid  = threadIdx.x;
    const int lane = tid & 63;
    const int w    = tid >> 6;
    const int q    = lane >> 4;
    const int ln   = lane & 15;
    const int bid  = blockIdx.x;
    const int g    = bid >> 1;
    const int p    = bid & 1;
    const int peer = bid ^ 1;
    const int S    = g * 16;
    const int hb   = p * 8 + w;
    const int col  = hb * 16 + ln;        // global hidden col
    const int colp = w * 16 + ln;         // col within own half

    for (int i = tid; i < LDS_BYTES / 4; i += 512) ((int*)lds)[i] = 0;

    // weights: wt[ci][j], j order: 0,1=x; 2..5=own h; 6..9=peer h
    s16x8 wt[4][10];
#pragma unroll
    for (int ci = 0; ci < 4; ++ci) {
        const int ct = ci * 16 + hb;
#pragma unroll
        for (int j = 0; j < 10; ++j) {
            const int kf = (j < 2) ? j
                         : (j < 6 ? 2 + 4 * p + (j - 2)
                                  : 2 + 4 * (1 - p) + (j - 6));
            wt[ci][j] = fragbuf[(size_t)(ct * NKF + kf) * 64 + lane];
        }
    }
    float bs[4];
#pragma unroll
    for (int ci = 0; ci < 4; ++ci) bs[ci] = bias[(ci * 16 + hb) * 16 + ln];

    f32x4 cs = {0.f, 0.f, 0.f, 0.f};

    const int xrow = tid >> 5;
    const int xi   = (tid & 31) << 1;
    const float* xp0 = x + (size_t)(S + xrow) * IN_SZ + xi;
    float xv0 = xp0[0], xv1 = xp0[1];                       // x_0

    // stage x_0 into buf 0
    {
        const short h0 = f2bf(xv0), h1 = f2bf(xv1);
        const short l0 = f2bf(xv0 - bf2f(h0));
        const short l1 = f2bf(xv1 - bf2f(h1));
        *(s16x2*)aptr(lds, 0, xrow, xi * 2)       = (s16x2){h0, h1};
        *(s16x2*)aptr(lds, 0, xrow, 384 + xi * 2) = (s16x2){l0, l1};
    }
    {   // prefetch x_1
        const float* xp = xp0 + (size_t)(B_SZ * IN_SZ);
        xv0 = xp[0]; xv1 = xp[1];
    }
    char* peerL = lds + PEER_OFF;
    unsigned* psw = (unsigned*)(lds + PSW_OFF) + w * 272;   // wave-private 16x17
    // consumer staging roles: half (hi/lo), row m, 16B chunk
    const int sh = tid >> 8;              // 0:hi 1:lo
    const int sm = (tid >> 4) & 15;       // row
    const int sc = tid & 15;              // chunk
    unsigned rdy = 0;

    __syncthreads();

    for (int t = 0; t < T_SEQ; ++t) {
        const int cur = t & 1;
        char* mySlot = xbuf + (size_t)bid  * 16384 + (size_t)cur * 8192;
        char* pSlot  = xbuf + (size_t)peer * 16384 + (size_t)((t - 1) & 1) * 8192;
        const unsigned tgt = 8u * (unsigned)t;
        const bool fast = (t > 0) && __all((int)(rdy >= tgt));

        // ---- speculative peer-slice load (valid: rdy pre-checked LAST step)
        u64 pv0, pv1;
        const u64* psrc = (const u64*)(pSlot + sh * 4096 + sm * 256 + sc * 16);
        if (fast) {
            pv0 = __hip_atomic_load(psrc,     __ATOMIC_RELAXED, __HIP_MEMORY_SCOPE_AGENT);
            pv1 = __hip_atomic_load(psrc + 1, __ATOMIC_RELAXED, __HIP_MEMORY_SCOPE_AGENT);
        }

        // ---- x + own-half MFMAs (j = 0..5), overlap the peer RT ----
        f32x4 acc[4], acl[4];
#pragma unroll
        for (int ci = 0; ci < 4; ++ci) {
            acc[ci] = (f32x4){bs[ci], bs[ci], bs[ci], bs[ci]};
            acl[ci] = (f32x4){0.f, 0.f, 0.f, 0.f};
        }
#pragma unroll
        for (int j = 0; j < 6; ++j) {
            const s16x8 ah = *(const s16x8*)aptr(lds, cur, ln, j * 64 + q * 16);
            const s16x8 al = *(const s16x8*)aptr(lds, cur, ln, 384 + j * 64 + q * 16);
#pragma unroll
            for (int ci = 0; ci < 4; ++ci) {
                acc[ci] = __builtin_amdgcn_mfma_f32_16x16x32_bf16(ah, wt[ci][j], acc[ci], 0, 0, 0);
                acl[ci] = __builtin_amdgcn_mfma_f32_16x16x32_bf16(al, wt[ci][j], acl[ci], 0, 0, 0);
            }
        }

        // ---- peer half (j = 6..9) ----
        if (t > 0) {
            if (!fast) {        // slow path: spin (signal likely already sent)
                while (__hip_atomic_load(&flags[peer * 32], __ATOMIC_RELAXED,
                                         __HIP_MEMORY_SCOPE_AGENT) < tgt)
                    __builtin_amdgcn_s_sleep(1);
                asm volatile("" ::: "memory");
                pv0 = __hip_atomic_load(psrc,     __ATOMIC_RELAXED, __HIP_MEMORY_SCOPE_AGENT);
                pv1 = __hip_atomic_load(psrc + 1, __ATOMIC_RELAXED, __HIP_MEMORY_SCOPE_AGENT);
            }
            // stage 16B to peer LDS region [row][hi 272 | lo 272]
            *(u64x2*)(peerL + sm * PROW + sh * 272 + sc * 16) = (u64x2){pv0, pv1};
            __syncthreads();
#pragma unroll
            for (int jj = 0; jj < 4; ++jj) {
                const s16x8 ah = *(const s16x8*)(peerL + ln * PROW + jj * 64 + q * 16);
                const s16x8 al = *(const s16x8*)(peerL + ln * PROW + 272 + jj * 64 + q * 16);
#pragma unroll
                for (int ci = 0; ci < 4; ++ci) {
                    acc[ci] = __builtin_amdgcn_mfma_f32_16x16x32_bf16(ah, wt[ci][6 + jj], acc[ci], 0, 0, 0);
                    acl[ci] = __builtin_amdgcn_mfma_f32_16x16x32_bf16(al, wt[ci][6 + jj], acl[ci], 0, 0, 0);
                }
            }
        }
#pragma unroll
        for (int ci = 0; ci < 4; ++ci) acc[ci] += acl[ci];

        // ---- cell update ----
        // C/D layout (m89): col = lane&15, row = (lane>>4)*4 + r
        const bool last = (t == T_SEQ - 1);
        float hvr[4]; float cfr[4]; unsigned pu[4];
#pragma unroll
        for (int r = 0; r < 4; ++r) {
            const float fv = fsigmoid(acc[0][r]);
            const float iv = fsigmoid(acc[1][r]);
            const float ov = fsigmoid(acc[2][r]);
            const float gv = ftanh(acc[3][r]);
            const float cf = fv * cs[r] + iv * gv;
            cs[r] = cf; cfr[r] = cf;
            const float hv = ov * ftanh(cf);
            hvr[r] = hv;
            const short hh = f2bf(hv);
            const short hl = f2bf(hv - bf2f(hh));
            pu[r] = ((unsigned)(unsigned short)hh)
                  | (((unsigned)(unsigned short)hl) << 16);
        }

        // ---- publish: wave-private LDS transpose -> [row][col] hi/lo ----
#pragma unroll
        for (int r = 0; r < 4; ++r) psw[ln * 17 + q * 4 + r] = pu[r];
        {
            const int m2 = lane & 15;          // row role
            const int cc = lane >> 4;          // col-chunk role
            const unsigned t0 = psw[(cc * 4 + 0) * 17 + m2];
            const unsigned t1 = psw[(cc * 4 + 1) * 17 + m2];
            const unsigned t2 = psw[(cc * 4 + 2) * 17 + m2];
            const unsigned t3 = psw[(cc * 4 + 3) * 17 + m2];
            const u64 hi64 = (u64)(t0 & 0xffffu) | ((u64)(t1 & 0xffffu) << 16)
                           | ((u64)(t2 & 0xffffu) << 32) | ((u64)(t3 & 0xffffu) << 48);
            const u64 lo64 = (u64)(t0 >> 16) | ((u64)(t1 >> 16) << 16)
                           | ((u64)(t2 >> 16) << 32) | ((u64)(t3 >> 16) << 48);
            const int off = m2 * 256 + w * 32 + cc * 8;
            __hip_atomic_store((u64*)(mySlot + off),        hi64, __ATOMIC_RELAXED, __HIP_MEMORY_SCOPE_AGENT);
            __hip_atomic_store((u64*)(mySlot + 4096 + off), lo64, __ATOMIC_RELAXED, __HIP_MEMORY_SCOPE_AGENT);
        }
        // drain publish stores to LLC, then signal (one inc per wave)
        asm volatile("s_waitcnt vmcnt(0)" ::: "memory");
        if (lane == 0)
            (void)__hip_atomic_fetch_add(&flags[bid * 32], 1u, __ATOMIC_RELAXED,
                                         __HIP_MEMORY_SCOPE_AGENT);

        // ---- off-critical-path tail ----
        float* hs = out + (size_t)t * (B_SZ * H_SZ) + (size_t)S * H_SZ;
#pragma unroll
        for (int r = 0; r < 4; ++r) {
            const int m = q * 4 + r;
            __builtin_nontemporal_store(hvr[r], hs + m * H_SZ + col);
            *aptr(lds, cur ^ 1, m, 128 + colp * 2) = (short)(pu[r] & 0xffffu);
            *aptr(lds, cur ^ 1, m, 512 + colp * 2) = (short)(pu[r] >> 16);
            if (last) {
                float* fin = out + (size_t)T_SEQ * B_SZ * H_SZ;
                fin[(S + m) * H_SZ + col] = hvr[r];
                fin[B_SZ * H_SZ + (S + m) * H_SZ + col] = cfr[r];
            }
        }
        {   // stage x_{t+1} (prefetched), prefetch x_{t+2}
            const short h0 = f2bf(xv0), h1 = f2bf(xv1);
            const short l0 = f2bf(xv0 - bf2f(h0));
            const short l1 = f2bf(xv1 - bf2f(h1));
            *(s16x2*)aptr(lds, cur ^ 1, xrow, xi * 2)       = (s16x2){h0, h1};
            *(s16x2*)aptr(lds, cur ^ 1, xrow, 384 + xi * 2) = (s16x2){l0, l1};
            const int tn = (t + 2 < T_SEQ) ? t + 2 : T_SEQ - 1;
            const float* xp = xp0 + (size_t)tn * (B_SZ * IN_SZ);
            xv0 = xp[0]; xv1 = xp[1];
        }
        // pre-check peer flag for NEXT step (gates next spec load; RT hidden)
        rdy = __hip_atomic_load(&flags[peer * 32], __ATOMIC_RELAXED,
                                __HIP_MEMORY_SCOPE_AGENT);
        __syncthreads();
    }
}

extern "C" void kernel_launch(void* const* d_in, const int* in_sizes, int n_in,
                              void* d_out, int out_size, void* d_ws, size_t ws_size,
                              hipStream_t stream) {
    const float* x  = (const float*)d_in[0];
    const float* Wx = (const float*)d_in[1];
    const float* Wh = (const float*)d_in[2];
    const float* bx = (const float*)d_in[3];
    const float* bh = (const float*)d_in[4];
    float* out = (float*)d_out;

    s16x8*    fragbuf = (s16x8*)d_ws;
    float*    bias    = (float*)((char*)d_ws + BIAS_OFF);
    unsigned* flags   = (unsigned*)((char*)d_ws + FLAGS_OFF);
    char*     xbuf    = (char*)d_ws + XBUF_OFF;

    repack_kernel<<<NCT * NKF, 64, 0, stream>>>(Wx, Wh, bx, bh, fragbuf, bias);
    init_flags<<<1, 256, 0, stream>>>(flags);
    lstm_persist<<<32, 512, 0, stream>>>(x, fragbuf, bias, out, flags, xbuf);
}